// Round 8
// baseline (197.915 us; speedup 1.0000x reference)
//
#include <hip/hip_runtime.h>
#include <math.h>
#include <utility>

#define Bb 2
#define Tt 8
#define Cc 16
#define Hh 64
#define Ww 64
#define Dd 32
#define HID 128
#define NPIX 4096
#define NIMG 256   // B*T*C

typedef unsigned short ushort_t;
typedef unsigned int uint_t;
typedef __attribute__((ext_vector_type(8))) short short8;
typedef __attribute__((ext_vector_type(4))) float f32x4;
union U16 { uint4 u; short8 s; };

__device__ __forceinline__ float sp_f(float x) {           // softplus
    return (x > 20.f) ? x : log1pf(expf(x));
}

__device__ __forceinline__ ushort_t f2bf(float f) {        // round-to-nearest-even
    uint_t u = __float_as_uint(f);
    uint_t r = (u + 0x7fffu + ((u >> 16) & 1u)) >> 16;
    return (ushort_t)r;
}
__device__ __forceinline__ float bf2f(ushort_t h) { return __uint_as_float(((uint_t)h) << 16); }

// pack two f32 (truncate) into bf16 pair via v_perm_b32
__device__ __forceinline__ uint_t packbf(float hi, float lo) {
    return __builtin_amdgcn_perm(__float_as_uint(hi), __float_as_uint(lo), 0x07060302u);
}
__device__ __forceinline__ uint4 synth8(const float* gf, float xs) {
    uint4 r;
    r.x = packbf(gf[1] * xs, gf[0] * xs);
    r.y = packbf(gf[3] * xs, gf[2] * xs);
    r.z = packbf(gf[5] * xs, gf[4] * xs);
    r.w = packbf(gf[7] * xs, gf[6] * xs);
    return r;
}
__device__ __forceinline__ void expand8(uint4 v, float* f) {
    f[0] = __uint_as_float(v.x << 16); f[1] = __uint_as_float(v.x & 0xffff0000u);
    f[2] = __uint_as_float(v.y << 16); f[3] = __uint_as_float(v.y & 0xffff0000u);
    f[4] = __uint_as_float(v.z << 16); f[5] = __uint_as_float(v.z & 0xffff0000u);
    f[6] = __uint_as_float(v.w << 16); f[7] = __uint_as_float(v.w & 0xffff0000u);
}

// compile-time-unroll helper
template <typename F, int... Is>
__device__ __forceinline__ void unroll_impl(F&& f, std::integer_sequence<int, Is...>) {
    (f(std::integral_constant<int, Is>{}), ...);
}
template <int N, typename F>
__device__ __forceinline__ void cunroll(F&& f) {
    unroll_impl(f, std::make_integer_sequence<int, N>{});
}

#define MFMA16(a, b, c) __builtin_amdgcn_mfma_f32_16x16x32_bf16((a), (b), (c), 0, 0, 0)

// ---------------- complex helpers + DFT8 ----------------
struct cpx { float r, i; };
__device__ __forceinline__ cpx cadd(cpx a, cpx b) { return {a.r + b.r, a.i + b.i}; }
__device__ __forceinline__ cpx csub(cpx a, cpx b) { return {a.r - b.r, a.i - b.i}; }
__device__ __forceinline__ cpx cmulw(cpx a, float wr, float wi) {
    return {a.r * wr - a.i * wi, a.r * wi + a.i * wr};
}
template<int S>
__device__ __forceinline__ cpx cmulSi(cpx a) {   // a * (S*i)
    return {-(float)S * a.i, (float)S * a.r};
}
template<int S>
__device__ __forceinline__ void dft8(cpx* y) {
    const float C = 0.70710678118654752f;
    cpx t0 = cadd(y[0], y[4]), t1 = csub(y[0], y[4]);
    cpx t2 = cadd(y[2], y[6]), t3 = csub(y[2], y[6]);
    cpx e0 = cadd(t0, t2), e2 = csub(t0, t2);
    cpx t3i = cmulSi<S>(t3);
    cpx e1 = cadd(t1, t3i), e3 = csub(t1, t3i);
    cpx u0 = cadd(y[1], y[5]), u1 = csub(y[1], y[5]);
    cpx u2 = cadd(y[3], y[7]), u3 = csub(y[3], y[7]);
    cpx o0 = cadd(u0, u2), o2 = csub(u0, u2);
    cpx u3i = cmulSi<S>(u3);
    cpx o1 = cadd(u1, u3i), o3 = csub(u1, u3i);
    o1 = cmulw(o1, C, (float)S * C);
    o2 = cmulSi<S>(o2);
    o3 = cmulw(o3, -C, (float)S * C);
    y[0] = cadd(e0, o0); y[4] = csub(e0, o0);
    y[1] = cadd(e1, o1); y[5] = csub(e1, o1);
    y[2] = cadd(e2, o2); y[6] = csub(e2, o2);
    y[3] = cadd(e3, o3); y[7] = csub(e3, o3);
}

// 2D 64x64 radix-8 FFT, 512 threads, natural in/out, in-place.
template<int S>
__device__ __forceinline__ void fft2d_r8(float* reM, float* imM,
                                         const float* twr, const float* twi, int tid) {
    int j = tid & 63, g = tid >> 6;
    {   // row pass, stage A
        cpx y[8];
        #pragma unroll
        for (int n1 = 0; n1 < 8; ++n1) {
            int a = j * 65 + n1 * 8 + g;
            y[n1] = {reM[a], imM[a]};
        }
        dft8<S>(y);
        #pragma unroll
        for (int k1 = 0; k1 < 8; ++k1) {
            int m = (g * k1) & 63;
            cpx b = cmulw(y[k1], twr[m], twi[m]);
            int a = j * 65 + k1 * 8 + g;
            reM[a] = b.r; imM[a] = b.i;
        }
    }
    __syncthreads();
    {   // row pass, stage B
        cpx y[8];
        #pragma unroll
        for (int n2 = 0; n2 < 8; ++n2) {
            int a = j * 65 + g * 8 + n2;
            y[n2] = {reM[a], imM[a]};
        }
        dft8<S>(y);
        __syncthreads();
        #pragma unroll
        for (int k2 = 0; k2 < 8; ++k2) {
            int a = j * 65 + g + k2 * 8;
            reM[a] = y[k2].r; imM[a] = y[k2].i;
        }
    }
    __syncthreads();
    {   // column pass, stage A
        cpx y[8];
        #pragma unroll
        for (int n1 = 0; n1 < 8; ++n1) {
            int a = (n1 * 8 + g) * 65 + j;
            y[n1] = {reM[a], imM[a]};
        }
        dft8<S>(y);
        #pragma unroll
        for (int k1 = 0; k1 < 8; ++k1) {
            int m = (g * k1) & 63;
            cpx b = cmulw(y[k1], twr[m], twi[m]);
            int a = (k1 * 8 + g) * 65 + j;
            reM[a] = b.r; imM[a] = b.i;
        }
    }
    __syncthreads();
    {   // column pass, stage B
        cpx y[8];
        #pragma unroll
        for (int n2 = 0; n2 < 8; ++n2) {
            int a = (g * 8 + n2) * 65 + j;
            y[n2] = {reM[a], imM[a]};
        }
        dft8<S>(y);
        __syncthreads();
        #pragma unroll
        for (int k2 = 0; k2 < 8; ++k2) {
            int a = (g + k2 * 8) * 65 + j;
            reM[a] = y[k2].r; imM[a] = y[k2].i;
        }
    }
    __syncthreads();
}

// ---------------- K1: conv (blocks 0..511) + weight prep (blocks 512..551) -----------
// B1f fragment order: uint4 index ((s*4+ch)*64+lane); chunks 0,1 = antisymmetrized
// (J - J^T) rows (n = ch*16 + (lane&15)); chunks 2,3 = P rows (Pg). s=32 -> bias.
// B2f: ((s*2+ch)*64+lane).
__global__ __launch_bounds__(256)
void k_conv(const float* __restrict__ xr, const float* __restrict__ xi,
            const float* __restrict__ cw, const float* __restrict__ cb,
            float2* __restrict__ x1,
            const float* __restrict__ JW, const float* __restrict__ Jb,
            const float* __restrict__ RW, const float* __restrict__ Rb,
            const float* __restrict__ W1, const float* __restrict__ dtp,
            const float* __restrict__ dt_param,
            ushort_t* __restrict__ B1f, ushort_t* __restrict__ B2f,
            ushort_t* __restrict__ w1n, ushort_t* __restrict__ w1t,
            float* __restrict__ dts_out) {
    __shared__ float sre[Cc][18][18];
    __shared__ float sim[Cc][18][18];
    __shared__ float swt[8 * 16 * 12];
    __shared__ float sb[8];
    int tid = threadIdx.x;
    if (blockIdx.x >= 512) {                   // ---- prep path ----
        const int N1 = 33 * 2048, N2 = 33 * 1024, N3 = 4096;
        int i = (blockIdx.x - 512) * 256 + tid;
        for (; i < N1 + N2 + N3; i += 40 * 256) {
            if (i < N1) {
                int s = i / 2048; int r = i % 2048;
                int ch = r >> 9; int lane = (r >> 3) & 63; int e = i & 7;
                int n = ch * 16 + (lane & 15);
                int k = s * 32 + ((lane >> 4) << 3) + e;
                float v;
                if (k < 1024) {
                    int d = k >> 5, rr = k & 31;
                    if (n < 32) v = JW[d * 1024 + n * 32 + rr] - JW[d * 1024 + rr * 32 + n];
                    else        v = RW[d * 1024 + (n - 32) * 32 + rr];
                } else {
                    int rr = k - 1024;
                    if (n < 32) v = Jb[n * 32 + rr] - Jb[rr * 32 + n];
                    else        v = Rb[(n - 32) * 32 + rr];
                }
                B1f[i] = f2bf(v);
            } else if (i < N1 + N2) {
                int i2 = i - N1;
                int s = i2 / 1024; int r = i2 % 1024;
                int ch = r >> 9; int lane = (r >> 3) & 63; int e = i2 & 7;
                int n = ch * 16 + (lane & 15);
                int k = s * 32 + ((lane >> 4) << 3) + e;
                float v;
                if (k < 1024) {
                    int d = k >> 5, kk = k & 31;
                    v = RW[d * 1024 + kk * 32 + n];
                } else {
                    v = Rb[(k - 1024) * 32 + n];
                }
                B2f[i2] = f2bf(v);
            } else {
                int i3 = i - N1 - N2;
                int d = i3 >> 7, h = i3 & 127;
                ushort_t v = f2bf(W1[i3]);
                w1n[i3] = v;
                w1t[h * 32 + d] = v;
            }
        }
        if (blockIdx.x == 512 && tid == 0) {
            float s = 0.f;
            for (int c = 0; c < Cc; ++c) s += sp_f(dt_param[c]);
            dts_out[0] = dtp[0] * s * (1.f / Cc);
        }
        return;
    }
    // ---- conv path ----
    int blk = blockIdx.x;
    int bt = blk >> 5;
    int sub = blk & 31;
    int tile = sub >> 1, cohalf = sub & 1;
    int ty0 = (tile >> 2) * 16, tx0 = (tile & 3) * 16;
    for (int i = tid; i < 8 * 16 * 9; i += 256) {
        int g = i / 9, k = i % 9;
        swt[g * 12 + k] = cw[cohalf * 8 * 144 + i];
    }
    if (tid < 8) sb[tid] = cb[cohalf * 8 + tid];
    for (int i = tid; i < Cc * 18 * 18; i += 256) {
        int ci = i / 324; int r = i % 324; int y = r / 18, x = r % 18;
        int gy = ty0 + y - 1, gx = tx0 + x - 1;
        float vr = 0.f, vi = 0.f;
        if (gy >= 0 && gy < Hh && gx >= 0 && gx < Ww) {
            int gidx = (bt * Cc + ci) * NPIX + gy * Ww + gx;
            vr = xr[gidx]; vi = xi[gidx];
        }
        sre[ci][y][x] = vr; sim[ci][y][x] = vi;
    }
    __syncthreads();
    int py = tid >> 4, px = tid & 15;
    int gy = ty0 + py, gx = tx0 + px;
    float ar[8], ai[8];
    #pragma unroll
    for (int oc = 0; oc < 8; ++oc) {
        int cg = cohalf * 8 + oc;
        ar[oc] = sre[cg][py + 1][px + 1] + sb[oc];
        ai[oc] = sim[cg][py + 1][px + 1] + sb[oc];
    }
    for (int ci = 0; ci < Cc; ++ci) {
        float nr[9], ni[9];
        #pragma unroll
        for (int dy = 0; dy < 3; ++dy)
            #pragma unroll
            for (int dx = 0; dx < 3; ++dx) {
                nr[dy * 3 + dx] = sre[ci][py + dy][px + dx];
                ni[dy * 3 + dx] = sim[ci][py + dy][px + dx];
            }
        #pragma unroll
        for (int oc = 0; oc < 8; ++oc) {
            const float* wp = &swt[(oc * 16 + ci) * 12];
            float4 w0 = *(const float4*)&wp[0];
            float4 w1 = *(const float4*)&wp[4];
            float w8 = wp[8];
            ar[oc] += w0.x * nr[0] + w0.y * nr[1] + w0.z * nr[2]
                    + w0.w * nr[3] + w1.x * nr[4] + w1.y * nr[5]
                    + w1.z * nr[6] + w1.w * nr[7] + w8 * nr[8];
            ai[oc] += w0.x * ni[0] + w0.y * ni[1] + w0.z * ni[2]
                    + w0.w * ni[3] + w1.x * ni[4] + w1.y * ni[5]
                    + w1.z * ni[6] + w1.w * ni[7] + w8 * ni[8];
        }
    }
    #pragma unroll
    for (int oc = 0; oc < 8; ++oc)
        x1[(bt * Cc + cohalf * 8 + oc) * NPIX + gy * Ww + gx] = make_float2(ar[oc], ai[oc]);
}

// ---------------- K2: X2f = fft2_std(x1) * (1 + filt), 512 threads --------------------
__global__ __launch_bounds__(512)
void k_fft_fwd(const float2* __restrict__ x1,
               const float* __restrict__ spec_re, const float* __restrict__ spec_im,
               float2* __restrict__ X2f) {
    int img = blockIdx.x;
    int c = img % Cc;
    int tid = threadIdx.x;
    __shared__ float re[64 * 65], im[64 * 65];
    __shared__ float twr[64], twi[64];
    if (tid < 64) {
        float ang = -0.098174770424681038798f * (float)tid;  // S=-1
        twr[tid] = cosf(ang); twi[tid] = sinf(ang);
    }
    const float2* src = x1 + (size_t)img * NPIX;
    for (int idx = tid; idx < NPIX; idx += 512) {
        int h = idx >> 6, w = idx & 63;
        float2 v = src[idx];
        re[h * 65 + w] = v.x; im[h * 65 + w] = v.y;
    }
    __syncthreads();
    fft2d_r8<-1>(re, im, twr, twi, tid);
    const float* fr = spec_re + c * NPIX;
    const float* fi = spec_im + c * NPIX;
    float2* dst = X2f + (size_t)img * NPIX;
    for (int idx = tid; idx < NPIX; idx += 512) {
        int h = idx >> 6, w = idx & 63;
        float xr_ = re[h * 65 + w], xi_ = im[h * 65 + w];
        float gr = 1.f + fr[idx], gi = fi[idx];
        dst[idx] = make_float2(xr_ * gr - xi_ * gi, xi_ * gr + xr_ * gi);
    }
}

// ---------------- K3: scan2 — S = Z + z, per-half conj-coeff scan ---------------------
__global__ __launch_bounds__(256)
void k_scan2(const float2* __restrict__ Z,
             const float* __restrict__ lam_re, const float* __restrict__ lam_im,
             const float* __restrict__ dt_param, const float* __restrict__ dtp,
             float2* __restrict__ S) {
    int id = blockIdx.x * 256 + threadIdx.x;      // 131072 = B*C*H*W
    int w = id & 63;
    int c = (id >> 12) & 15;
    int b = id >> 16;
    float dte = dtp[0] * sp_f(dt_param[c]);
    float ea = expf(-sp_f(lam_re[c]) * dte);
    float ph = lam_im[c] * dte;
    float Ar = ea * cosf(ph), Ai = ea * sinf(ph);
    if (w > 32) Ai = -Ai;
    bool sc = (w == 0) || (w == 32);
    int pix = id & (NPIX - 1);
    int base = (b * Tt * Cc + c) * NPIX + pix;
    float s1r = 0.f, s1i = 0.f, s2r = 0.f, s2i = 0.f;
    #pragma unroll
    for (int t = 0; t < Tt; ++t) {
        int idx = base + t * (Cc * NPIX);
        float2 zv = Z[idx];
        float nr = Ar * s1r - Ai * s1i + zv.x;
        float ni = Ar * s1i + Ai * s1r + zv.y;
        s1r = nr; s1i = ni;
        float zr, zi;
        if (sc) {
            nr = Ar * s2r + Ai * s2i + zv.x;
            ni = Ar * s2i - Ai * s2r + zv.y;
            s2r = nr; s2i = ni;
            zr = 0.5f * (s1r + s2r); zi = 0.5f * (s1i + s2i);
        } else { zr = s1r; zi = s1i; }
        S[idx] = make_float2(zv.x + zr, zv.y + zi);
    }
}

// ---------------- K5: field = ifft2_std(S) + noise, 512 threads -----------------------
__global__ __launch_bounds__(512)
void k_fft_inv(const float2* __restrict__ Sp,
               const float* __restrict__ noise_r, const float* __restrict__ noise_i,
               const float* __restrict__ sigma_p, const float* __restrict__ dts_p,
               float2* __restrict__ xf) {
    int img = blockIdx.x; int tid = threadIdx.x;
    __shared__ float re[64 * 65], im[64 * 65];
    __shared__ float twr[64], twi[64];
    if (tid < 64) {
        float ang = 0.098174770424681038798f * (float)tid;   // S=+1
        twr[tid] = cosf(ang); twi[tid] = sinf(ang);
    }
    const float2* src = Sp + (size_t)img * NPIX;
    for (int idx = tid; idx < NPIX; idx += 512) {
        int h = idx >> 6, w = idx & 63;
        float2 v = src[idx];
        re[h * 65 + w] = v.x; im[h * 65 + w] = v.y;
    }
    __syncthreads();
    fft2d_r8<1>(re, im, twr, twi, tid);
    float ns = sigma_p[0] * sqrtf(dts_p[0]);
    const float inv = 1.f / 4096.f;
    float2* dst = xf + (size_t)img * NPIX;
    const float* nr = noise_r + (size_t)img * NPIX;
    const float* ni = noise_i + (size_t)img * NPIX;
    for (int idx = tid; idx < NPIX; idx += 512) {
        int h = idx >> 6, w = idx & 63;
        dst[idx] = make_float2(re[h * 65 + w] * inv + ns * nr[idx],
                               im[h * 65 + w] * inv + ns * ni[idx]);
    }
}

// ---------------- K6: PH layer — barrier-free, wave-owned 64 rows, Jdiff kernel -------
// 512 blocks x 128 threads (2 waves). Thread p <-> position p <-> matrix row p.
// Every LDS region is wave-private -> ZERO __syncthreads (DS in-order + lgkmcnt).
__global__ __launch_bounds__(128, 1)
void k_ph(const float2* __restrict__ field,
          const float* __restrict__ ln_g, const float* __restrict__ ln_b,
          const float* __restrict__ b1, const float* __restrict__ w2,
          const ushort_t* __restrict__ w1n, const ushort_t* __restrict__ w1t,
          const ushort_t* __restrict__ B1f, const ushort_t* __restrict__ B2f,
          const float* __restrict__ dts_p,
          float* __restrict__ out) {
    __shared__ ushort_t xin_s[128 * 40];            // 10240 B
    __shared__ ushort_t g_s[128 * 40];              // 10240 B
    __shared__ ushort_t A_st[2 * 4352];             // 17408 B: per-wave 32x136 slice
                                                    // (t staging -> pg -> upd f32)
    int tid = threadIdx.x;
    int bt = blockIdx.x >> 5;
    int pix0 = (blockIdx.x & 31) << 7;
    int p = tid;
    int lane = tid & 63, wv = tid >> 6;
    int quad = lane >> 4, l15 = lane & 15;
    int m0 = wv * 64;
    ushort_t* slice = &A_st[wv * 4352];
    const f32x4 zero4 = {0.f, 0.f, 0.f, 0.f};

    // ---- Phase 1: thread-local LayerNorm -> xin_s (bf16, row p) ----
    const float2* fbase = field + ((size_t)bt * 16) * NPIX + pix0 + p;
    {
        float2 xv[16];
        float s1 = 0.f, s2 = 0.f;
        #pragma unroll
        for (int j = 0; j < 16; ++j) {
            xv[j] = fbase[j * NPIX];
            s1 += xv[j].x + xv[j].y;
            s2 += xv[j].x * xv[j].x + xv[j].y * xv[j].y;
        }
        float mu = s1 * 0.03125f;
        float var = s2 * 0.03125f - mu * mu;
        float rs = rsqrtf(var + 1e-5f);
        #pragma unroll
        for (int j = 0; j < 16; ++j) {
            xin_s[p * 40 + j]      = f2bf((xv[j].x - mu) * rs * ln_g[j] + ln_b[j]);
            xin_s[p * 40 + 16 + j] = f2bf((xv[j].y - mu) * rs * ln_g[16 + j] + ln_b[16 + j]);
        }
    }

    // ---- z GEMM + t act + g GEMM, per 32-row half (wave-private slice) ----
    #pragma unroll
    for (int hh = 0; hh < 2; ++hh) {
        int hb = m0 + hh * 32;
        U16 az[2];
        #pragma unroll
        for (int mt2 = 0; mt2 < 2; ++mt2)
            az[mt2].u = *(const uint4*)&xin_s[(hb + mt2 * 16 + l15) * 40 + quad * 8];
        f32x4 zacc[2][8];
        #pragma unroll
        for (int mt2 = 0; mt2 < 2; ++mt2)
            #pragma unroll
            for (int nt = 0; nt < 8; ++nt) zacc[mt2][nt] = zero4;
        #pragma unroll
        for (int nt = 0; nt < 8; ++nt) {
            U16 bz;
            bz.u = *(const uint4*)&w1t[(nt * 16 + l15) * 32 + quad * 8];
            zacc[0][nt] = MFMA16(az[0].s, bz.s, zacc[0][nt]);
            zacc[1][nt] = MFMA16(az[1].s, bz.s, zacc[1][nt]);
        }
        #pragma unroll
        for (int nt = 0; nt < 8; ++nt) {
            int col = nt * 16 + l15;
            float b1v = b1[col], w2v = w2[col];
            #pragma unroll
            for (int mt2 = 0; mt2 < 2; ++mt2) {
                #pragma unroll
                for (int r = 0; r < 4; ++r) {
                    int lrow = mt2 * 16 + quad * 4 + r;
                    float z = zacc[mt2][nt][r] + b1v;
                    float s = 1.f / (1.f + expf(-z));
                    float t = s * (1.f + z * (1.f - s)) * w2v;
                    slice[lrow * 136 + col] = f2bf(t);
                }
            }
        }
        // g GEMM: K=128 over t rows (own slice, own wave -> no barrier)
        f32x4 gacc[2][2];
        gacc[0][0] = zero4; gacc[0][1] = zero4; gacc[1][0] = zero4; gacc[1][1] = zero4;
        #pragma unroll
        for (int q = 0; q < 4; ++q) {
            U16 ag[2];
            #pragma unroll
            for (int mt2 = 0; mt2 < 2; ++mt2)
                ag[mt2].u = *(const uint4*)&slice[(mt2 * 16 + l15) * 136 + q * 32 + quad * 8];
            #pragma unroll
            for (int nt2 = 0; nt2 < 2; ++nt2) {
                U16 bg;
                bg.u = *(const uint4*)&w1n[(nt2 * 16 + l15) * 128 + q * 32 + quad * 8];
                gacc[0][nt2] = MFMA16(ag[0].s, bg.s, gacc[0][nt2]);
                gacc[1][nt2] = MFMA16(ag[1].s, bg.s, gacc[1][nt2]);
            }
        }
        #pragma unroll
        for (int mt2 = 0; mt2 < 2; ++mt2)
            #pragma unroll
            for (int nt2 = 0; nt2 < 2; ++nt2)
                #pragma unroll
                for (int r = 0; r < 4; ++r)
                    g_s[(hb + mt2 * 16 + quad * 4 + r) * 40 + nt2 * 16 + l15] =
                        f2bf(gacc[mt2][nt2][r]);
    }

    // ---- K-loop setup ----
    const ushort_t* xr[4];
    uint4 gvp[4];
    float gf[4][8];
    #pragma unroll
    for (int mt = 0; mt < 4; ++mt) {
        int row = m0 + mt * 16 + l15;
        xr[mt] = &xin_s[row * 40];
        gvp[mt] = *(const uint4*)&g_s[row * 40 + quad * 8];
        expand8(gvp[mt], gf[mt]);
    }
    const uint4* B1v = (const uint4*)B1f;
    const uint4* B2v = (const uint4*)B2f;

    // ---- pass 1: [Jd-bilinear(2ch) | Pg(2ch)] , s=0..32 (32=bias), depth-3 ring ----
    uint4 br[3][4];
    #pragma unroll
    for (int pf = 0; pf < 3; ++pf)
        #pragma unroll
        for (int ch = 0; ch < 4; ++ch)
            br[pf][ch] = B1v[(pf * 4 + ch) * 64 + lane];
    f32x4 acc1[4][4];
    #pragma unroll
    for (int ch = 0; ch < 4; ++ch)
        #pragma unroll
        for (int mt = 0; mt < 4; ++mt) acc1[ch][mt] = zero4;
    cunroll<33>([&](auto Sc) {
        constexpr int s = Sc.value;
        constexpr int slot = s % 3;
        U16 a[4];
        if constexpr (s < 32) {
            #pragma unroll
            for (int mt = 0; mt < 4; ++mt) {
                float xs = bf2f(xr[mt][s]);
                a[mt].u = synth8(gf[mt], xs);
            }
        } else {
            #pragma unroll
            for (int mt = 0; mt < 4; ++mt) a[mt].u = gvp[mt];
        }
        #pragma unroll
        for (int ch = 0; ch < 4; ++ch) {
            U16 b; b.u = br[slot][ch];
            #pragma unroll
            for (int mt = 0; mt < 4; ++mt)
                acc1[ch][mt] = MFMA16(a[mt].s, b.s, acc1[ch][mt]);
        }
        if constexpr (s + 3 < 33) {
            #pragma unroll
            for (int ch = 0; ch < 4; ++ch)
                br[slot][ch] = B1v[((s + 3) * 4 + ch) * 64 + lane];
        }
    });
    // Pg (chunks 2,3) -> wave-private pg region (reuses slice; t is dead)
    #pragma unroll
    for (int mt = 0; mt < 4; ++mt)
        #pragma unroll
        for (int c2 = 0; c2 < 2; ++c2)
            #pragma unroll
            for (int r = 0; r < 4; ++r)
                slice[(mt * 16 + quad * 4 + r) * 40 + c2 * 16 + l15] =
                    f2bf(acc1[2 + c2][mt][r]);

    // ---- pass 2: ptpg = (x (x) pg) @ B2^T, depth-3 ring ----
    uint4 pgp[4];
    float pgf[4][8];
    #pragma unroll
    for (int mt = 0; mt < 4; ++mt) {
        pgp[mt] = *(const uint4*)&slice[(mt * 16 + l15) * 40 + quad * 8];
        expand8(pgp[mt], pgf[mt]);
    }
    uint4 br2[3][2];
    #pragma unroll
    for (int pf = 0; pf < 3; ++pf) {
        br2[pf][0] = B2v[(pf * 2 + 0) * 64 + lane];
        br2[pf][1] = B2v[(pf * 2 + 1) * 64 + lane];
    }
    f32x4 acc2[2][4];
    #pragma unroll
    for (int ch = 0; ch < 2; ++ch)
        #pragma unroll
        for (int mt = 0; mt < 4; ++mt) acc2[ch][mt] = zero4;
    cunroll<33>([&](auto Sc) {
        constexpr int s = Sc.value;
        constexpr int slot = s % 3;
        U16 a[4];
        if constexpr (s < 32) {
            #pragma unroll
            for (int mt = 0; mt < 4; ++mt) {
                float xs = bf2f(xr[mt][s]);
                a[mt].u = synth8(pgf[mt], xs);
            }
        } else {
            #pragma unroll
            for (int mt = 0; mt < 4; ++mt) a[mt].u = pgp[mt];
        }
        #pragma unroll
        for (int ch = 0; ch < 2; ++ch) {
            U16 b; b.u = br2[slot][ch];
            #pragma unroll
            for (int mt = 0; mt < 4; ++mt)
                acc2[ch][mt] = MFMA16(a[mt].s, b.s, acc2[ch][mt]);
        }
        if constexpr (s + 3 < 33) {
            br2[slot][0] = B2v[((s + 3) * 2 + 0) * 64 + lane];
            br2[slot][1] = B2v[((s + 3) * 2 + 1) * 64 + lane];
        }
    });

    // ---- epilogue: upd = Jd-term - ptpg - 1e-4 g -> wave-private f32 slice ----
    float* updS = (float*)slice;                  // pg dead (pgp in regs)
    #pragma unroll
    for (int c2 = 0; c2 < 2; ++c2) {
        int col = c2 * 16 + l15;
        #pragma unroll
        for (int mt = 0; mt < 4; ++mt) {
            #pragma unroll
            for (int r = 0; r < 4; ++r) {
                int lrow = mt * 16 + quad * 4 + r;
                float gval = bf2f(g_s[(m0 + lrow) * 40 + col]);
                updS[lrow * 33 + col] = acc1[c2][mt][r] - acc2[c2][mt][r] - 1e-4f * gval;
            }
        }
    }
    float dts = dts_p[0];
    const float* updR = (const float*)&A_st[wv * 4352];
    int lr = tid & 63;
    #pragma unroll
    for (int cc = 0; cc < 16; ++cc) {
        float2 v = fbase[cc * NPIX];
        out[((size_t)bt * 32 + cc) * NPIX + pix0 + p] = v.x + dts * updR[lr * 33 + cc];
        out[((size_t)bt * 32 + 16 + cc) * NPIX + pix0 + p] = v.y + dts * updR[lr * 33 + 16 + cc];
    }
}

extern "C" void kernel_launch(void* const* d_in, const int* in_sizes, int n_in,
                              void* d_out, int out_size, void* d_ws, size_t ws_size,
                              hipStream_t stream) {
    const float* x_real   = (const float*)d_in[0];
    const float* x_imag   = (const float*)d_in[1];
    const float* dt       = (const float*)d_in[2];
    const float* conv_w   = (const float*)d_in[3];
    const float* conv_b   = (const float*)d_in[4];
    const float* spec_re  = (const float*)d_in[5];
    const float* spec_im  = (const float*)d_in[6];
    const float* lam_re   = (const float*)d_in[7];
    const float* lam_im   = (const float*)d_in[8];
    const float* dt_param = (const float*)d_in[9];
    const float* sigma    = (const float*)d_in[10];
    const float* noise_r  = (const float*)d_in[11];
    const float* noise_i  = (const float*)d_in[12];
    const float* ln_g     = (const float*)d_in[13];
    const float* ln_b     = (const float*)d_in[14];
    const float* W1       = (const float*)d_in[15];
    const float* b1       = (const float*)d_in[16];
    const float* w2       = (const float*)d_in[17];
    const float* Jg_W     = (const float*)d_in[19];
    const float* Jg_b     = (const float*)d_in[20];
    const float* Rg_W     = (const float*)d_in[21];
    const float* Rg_b     = (const float*)d_in[22];

    float2* wsA = (float2*)d_ws;              // x1, later final field
    float2* wsB = wsA + 1048576;              // Z spectrum
    float2* wsS = wsB + 1048576;              // assembled spectrum S

    ushort_t* B1f = (ushort_t*)(wsS + 1048576);
    ushort_t* B2f = B1f + 33 * 2048;
    ushort_t* w1n = B2f + 33 * 1024;
    ushort_t* w1t = w1n + 4096;
    float*    dts = (float*)(w1t + 4096);

    k_conv<<<552, 256, 0, stream>>>(x_real, x_imag, conv_w, conv_b, wsA,
                                    Jg_W, Jg_b, Rg_W, Rg_b, W1, dt, dt_param,
                                    B1f, B2f, w1n, w1t, dts);
    k_fft_fwd<<<NIMG, 512, 0, stream>>>(wsA, spec_re, spec_im, wsB);
    k_scan2<<<512, 256, 0, stream>>>(wsB, lam_re, lam_im, dt_param, dt, wsS);
    k_fft_inv<<<NIMG, 512, 0, stream>>>(wsS, noise_r, noise_i, sigma, dts, wsA);
    k_ph<<<512, 128, 0, stream>>>(wsA, ln_g, ln_b, b1, w2, w1n, w1t, B1f, B2f, dts,
                                  (float*)d_out);
}

// Round 9
// 182.316 us; speedup vs baseline: 1.0856x; 1.0856x over previous
//
#include <hip/hip_runtime.h>
#include <math.h>
#include <utility>

#define Bb 2
#define Tt 8
#define Cc 16
#define Hh 64
#define Ww 64
#define Dd 32
#define HID 128
#define NPIX 4096
#define NIMG 256   // B*T*C

typedef unsigned short ushort_t;
typedef unsigned int uint_t;
typedef __attribute__((ext_vector_type(8))) short short8;
typedef __attribute__((ext_vector_type(4))) float f32x4;
union U16 { uint4 u; short8 s; };

__device__ __forceinline__ float sp_f(float x) {           // softplus
    return (x > 20.f) ? x : log1pf(expf(x));
}

__device__ __forceinline__ ushort_t f2bf(float f) {        // round-to-nearest-even
    uint_t u = __float_as_uint(f);
    uint_t r = (u + 0x7fffu + ((u >> 16) & 1u)) >> 16;
    return (ushort_t)r;
}
__device__ __forceinline__ float bf2f(ushort_t h) { return __uint_as_float(((uint_t)h) << 16); }

// pack two f32 (truncate) into bf16 pair via v_perm_b32
__device__ __forceinline__ uint_t packbf(float hi, float lo) {
    return __builtin_amdgcn_perm(__float_as_uint(hi), __float_as_uint(lo), 0x07060302u);
}
__device__ __forceinline__ uint4 synth8(const float* gf, float xs) {
    uint4 r;
    r.x = packbf(gf[1] * xs, gf[0] * xs);
    r.y = packbf(gf[3] * xs, gf[2] * xs);
    r.z = packbf(gf[5] * xs, gf[4] * xs);
    r.w = packbf(gf[7] * xs, gf[6] * xs);
    return r;
}
__device__ __forceinline__ void expand8(uint4 v, float* f) {
    f[0] = __uint_as_float(v.x << 16); f[1] = __uint_as_float(v.x & 0xffff0000u);
    f[2] = __uint_as_float(v.y << 16); f[3] = __uint_as_float(v.y & 0xffff0000u);
    f[4] = __uint_as_float(v.z << 16); f[5] = __uint_as_float(v.z & 0xffff0000u);
    f[6] = __uint_as_float(v.w << 16); f[7] = __uint_as_float(v.w & 0xffff0000u);
}

// compile-time-unroll helper
template <typename F, int... Is>
__device__ __forceinline__ void unroll_impl(F&& f, std::integer_sequence<int, Is...>) {
    (f(std::integral_constant<int, Is>{}), ...);
}
template <int N, typename F>
__device__ __forceinline__ void cunroll(F&& f) {
    unroll_impl(f, std::make_integer_sequence<int, N>{});
}

#define MFMA16(a, b, c) __builtin_amdgcn_mfma_f32_16x16x32_bf16((a), (b), (c), 0, 0, 0)

// ---------------- complex helpers + DFT8 ----------------
struct cpx { float r, i; };
__device__ __forceinline__ cpx cadd(cpx a, cpx b) { return {a.r + b.r, a.i + b.i}; }
__device__ __forceinline__ cpx csub(cpx a, cpx b) { return {a.r - b.r, a.i - b.i}; }
__device__ __forceinline__ cpx cmulw(cpx a, float wr, float wi) {
    return {a.r * wr - a.i * wi, a.r * wi + a.i * wr};
}
template<int S>
__device__ __forceinline__ cpx cmulSi(cpx a) {   // a * (S*i)
    return {-(float)S * a.i, (float)S * a.r};
}
template<int S>
__device__ __forceinline__ void dft8(cpx* y) {
    const float C = 0.70710678118654752f;
    cpx t0 = cadd(y[0], y[4]), t1 = csub(y[0], y[4]);
    cpx t2 = cadd(y[2], y[6]), t3 = csub(y[2], y[6]);
    cpx e0 = cadd(t0, t2), e2 = csub(t0, t2);
    cpx t3i = cmulSi<S>(t3);
    cpx e1 = cadd(t1, t3i), e3 = csub(t1, t3i);
    cpx u0 = cadd(y[1], y[5]), u1 = csub(y[1], y[5]);
    cpx u2 = cadd(y[3], y[7]), u3 = csub(y[3], y[7]);
    cpx o0 = cadd(u0, u2), o2 = csub(u0, u2);
    cpx u3i = cmulSi<S>(u3);
    cpx o1 = cadd(u1, u3i), o3 = csub(u1, u3i);
    o1 = cmulw(o1, C, (float)S * C);
    o2 = cmulSi<S>(o2);
    o3 = cmulw(o3, -C, (float)S * C);
    y[0] = cadd(e0, o0); y[4] = csub(e0, o0);
    y[1] = cadd(e1, o1); y[5] = csub(e1, o1);
    y[2] = cadd(e2, o2); y[6] = csub(e2, o2);
    y[3] = cadd(e3, o3); y[7] = csub(e3, o3);
}

// 2D 64x64 radix-8 FFT, 512 threads, natural in/out, in-place.
template<int S>
__device__ __forceinline__ void fft2d_r8(float* reM, float* imM,
                                         const float* twr, const float* twi, int tid) {
    int j = tid & 63, g = tid >> 6;
    {   // row pass, stage A
        cpx y[8];
        #pragma unroll
        for (int n1 = 0; n1 < 8; ++n1) {
            int a = j * 65 + n1 * 8 + g;
            y[n1] = {reM[a], imM[a]};
        }
        dft8<S>(y);
        #pragma unroll
        for (int k1 = 0; k1 < 8; ++k1) {
            int m = (g * k1) & 63;
            cpx b = cmulw(y[k1], twr[m], twi[m]);
            int a = j * 65 + k1 * 8 + g;
            reM[a] = b.r; imM[a] = b.i;
        }
    }
    __syncthreads();
    {   // row pass, stage B
        cpx y[8];
        #pragma unroll
        for (int n2 = 0; n2 < 8; ++n2) {
            int a = j * 65 + g * 8 + n2;
            y[n2] = {reM[a], imM[a]};
        }
        dft8<S>(y);
        __syncthreads();
        #pragma unroll
        for (int k2 = 0; k2 < 8; ++k2) {
            int a = j * 65 + g + k2 * 8;
            reM[a] = y[k2].r; imM[a] = y[k2].i;
        }
    }
    __syncthreads();
    {   // column pass, stage A
        cpx y[8];
        #pragma unroll
        for (int n1 = 0; n1 < 8; ++n1) {
            int a = (n1 * 8 + g) * 65 + j;
            y[n1] = {reM[a], imM[a]};
        }
        dft8<S>(y);
        #pragma unroll
        for (int k1 = 0; k1 < 8; ++k1) {
            int m = (g * k1) & 63;
            cpx b = cmulw(y[k1], twr[m], twi[m]);
            int a = (k1 * 8 + g) * 65 + j;
            reM[a] = b.r; imM[a] = b.i;
        }
    }
    __syncthreads();
    {   // column pass, stage B
        cpx y[8];
        #pragma unroll
        for (int n2 = 0; n2 < 8; ++n2) {
            int a = (g * 8 + n2) * 65 + j;
            y[n2] = {reM[a], imM[a]};
        }
        dft8<S>(y);
        __syncthreads();
        #pragma unroll
        for (int k2 = 0; k2 < 8; ++k2) {
            int a = (g + k2 * 8) * 65 + j;
            reM[a] = y[k2].r; imM[a] = y[k2].i;
        }
    }
    __syncthreads();
}

// ---------------- K1: conv (blocks 0..511) + weight prep (blocks 512..551) -----------
// B1f fragment order: uint4 index ((s*4+ch)*64+lane); chunks 0,1 = antisymmetrized
// (J - J^T) rows (n = ch*16 + (lane&15)); chunks 2,3 = P rows (Pg). s=32 -> bias.
// B2f: ((s*2+ch)*64+lane).
__global__ __launch_bounds__(256)
void k_conv(const float* __restrict__ xr, const float* __restrict__ xi,
            const float* __restrict__ cw, const float* __restrict__ cb,
            float2* __restrict__ x1,
            const float* __restrict__ JW, const float* __restrict__ Jb,
            const float* __restrict__ RW, const float* __restrict__ Rb,
            const float* __restrict__ W1, const float* __restrict__ dtp,
            const float* __restrict__ dt_param,
            ushort_t* __restrict__ B1f, ushort_t* __restrict__ B2f,
            ushort_t* __restrict__ w1n, ushort_t* __restrict__ w1t,
            float* __restrict__ dts_out) {
    __shared__ float sre[Cc][18][18];
    __shared__ float sim[Cc][18][18];
    __shared__ float swt[8 * 16 * 12];
    __shared__ float sb[8];
    int tid = threadIdx.x;
    if (blockIdx.x >= 512) {                   // ---- prep path ----
        const int N1 = 33 * 2048, N2 = 33 * 1024, N3 = 4096;
        int i = (blockIdx.x - 512) * 256 + tid;
        for (; i < N1 + N2 + N3; i += 40 * 256) {
            if (i < N1) {
                int s = i / 2048; int r = i % 2048;
                int ch = r >> 9; int lane = (r >> 3) & 63; int e = i & 7;
                int n = ch * 16 + (lane & 15);
                int k = s * 32 + ((lane >> 4) << 3) + e;
                float v;
                if (k < 1024) {
                    int d = k >> 5, rr = k & 31;
                    if (n < 32) v = JW[d * 1024 + n * 32 + rr] - JW[d * 1024 + rr * 32 + n];
                    else        v = RW[d * 1024 + (n - 32) * 32 + rr];
                } else {
                    int rr = k - 1024;
                    if (n < 32) v = Jb[n * 32 + rr] - Jb[rr * 32 + n];
                    else        v = Rb[(n - 32) * 32 + rr];
                }
                B1f[i] = f2bf(v);
            } else if (i < N1 + N2) {
                int i2 = i - N1;
                int s = i2 / 1024; int r = i2 % 1024;
                int ch = r >> 9; int lane = (r >> 3) & 63; int e = i2 & 7;
                int n = ch * 16 + (lane & 15);
                int k = s * 32 + ((lane >> 4) << 3) + e;
                float v;
                if (k < 1024) {
                    int d = k >> 5, kk = k & 31;
                    v = RW[d * 1024 + kk * 32 + n];
                } else {
                    v = Rb[(k - 1024) * 32 + n];
                }
                B2f[i2] = f2bf(v);
            } else {
                int i3 = i - N1 - N2;
                int d = i3 >> 7, h = i3 & 127;
                ushort_t v = f2bf(W1[i3]);
                w1n[i3] = v;
                w1t[h * 32 + d] = v;
            }
        }
        if (blockIdx.x == 512 && tid == 0) {
            float s = 0.f;
            for (int c = 0; c < Cc; ++c) s += sp_f(dt_param[c]);
            dts_out[0] = dtp[0] * s * (1.f / Cc);
        }
        return;
    }
    // ---- conv path ----
    int blk = blockIdx.x;
    int bt = blk >> 5;
    int sub = blk & 31;
    int tile = sub >> 1, cohalf = sub & 1;
    int ty0 = (tile >> 2) * 16, tx0 = (tile & 3) * 16;
    for (int i = tid; i < 8 * 16 * 9; i += 256) {
        int g = i / 9, k = i % 9;
        swt[g * 12 + k] = cw[cohalf * 8 * 144 + i];
    }
    if (tid < 8) sb[tid] = cb[cohalf * 8 + tid];
    for (int i = tid; i < Cc * 18 * 18; i += 256) {
        int ci = i / 324; int r = i % 324; int y = r / 18, x = r % 18;
        int gy = ty0 + y - 1, gx = tx0 + x - 1;
        float vr = 0.f, vi = 0.f;
        if (gy >= 0 && gy < Hh && gx >= 0 && gx < Ww) {
            int gidx = (bt * Cc + ci) * NPIX + gy * Ww + gx;
            vr = xr[gidx]; vi = xi[gidx];
        }
        sre[ci][y][x] = vr; sim[ci][y][x] = vi;
    }
    __syncthreads();
    int py = tid >> 4, px = tid & 15;
    int gy = ty0 + py, gx = tx0 + px;
    float ar[8], ai[8];
    #pragma unroll
    for (int oc = 0; oc < 8; ++oc) {
        int cg = cohalf * 8 + oc;
        ar[oc] = sre[cg][py + 1][px + 1] + sb[oc];
        ai[oc] = sim[cg][py + 1][px + 1] + sb[oc];
    }
    for (int ci = 0; ci < Cc; ++ci) {
        float nr[9], ni[9];
        #pragma unroll
        for (int dy = 0; dy < 3; ++dy)
            #pragma unroll
            for (int dx = 0; dx < 3; ++dx) {
                nr[dy * 3 + dx] = sre[ci][py + dy][px + dx];
                ni[dy * 3 + dx] = sim[ci][py + dy][px + dx];
            }
        #pragma unroll
        for (int oc = 0; oc < 8; ++oc) {
            const float* wp = &swt[(oc * 16 + ci) * 12];
            float4 w0 = *(const float4*)&wp[0];
            float4 w1 = *(const float4*)&wp[4];
            float w8 = wp[8];
            ar[oc] += w0.x * nr[0] + w0.y * nr[1] + w0.z * nr[2]
                    + w0.w * nr[3] + w1.x * nr[4] + w1.y * nr[5]
                    + w1.z * nr[6] + w1.w * nr[7] + w8 * nr[8];
            ai[oc] += w0.x * ni[0] + w0.y * ni[1] + w0.z * ni[2]
                    + w0.w * ni[3] + w1.x * ni[4] + w1.y * ni[5]
                    + w1.z * ni[6] + w1.w * ni[7] + w8 * ni[8];
        }
    }
    #pragma unroll
    for (int oc = 0; oc < 8; ++oc)
        x1[(bt * Cc + cohalf * 8 + oc) * NPIX + gy * Ww + gx] = make_float2(ar[oc], ai[oc]);
}

// ---------------- K2: X2f = fft2_std(x1) * (1 + filt), 512 threads --------------------
__global__ __launch_bounds__(512)
void k_fft_fwd(const float2* __restrict__ x1,
               const float* __restrict__ spec_re, const float* __restrict__ spec_im,
               float2* __restrict__ X2f) {
    int img = blockIdx.x;
    int c = img % Cc;
    int tid = threadIdx.x;
    __shared__ float re[64 * 65], im[64 * 65];
    __shared__ float twr[64], twi[64];
    if (tid < 64) {
        float ang = -0.098174770424681038798f * (float)tid;  // S=-1
        twr[tid] = cosf(ang); twi[tid] = sinf(ang);
    }
    const float2* src = x1 + (size_t)img * NPIX;
    for (int idx = tid; idx < NPIX; idx += 512) {
        int h = idx >> 6, w = idx & 63;
        float2 v = src[idx];
        re[h * 65 + w] = v.x; im[h * 65 + w] = v.y;
    }
    __syncthreads();
    fft2d_r8<-1>(re, im, twr, twi, tid);
    const float* fr = spec_re + c * NPIX;
    const float* fi = spec_im + c * NPIX;
    float2* dst = X2f + (size_t)img * NPIX;
    for (int idx = tid; idx < NPIX; idx += 512) {
        int h = idx >> 6, w = idx & 63;
        float xr_ = re[h * 65 + w], xi_ = im[h * 65 + w];
        float gr = 1.f + fr[idx], gi = fi[idx];
        dst[idx] = make_float2(xr_ * gr - xi_ * gi, xi_ * gr + xr_ * gi);
    }
}

// ---------------- K3: scan2 — S = Z + z, per-half conj-coeff scan ---------------------
__global__ __launch_bounds__(256)
void k_scan2(const float2* __restrict__ Z,
             const float* __restrict__ lam_re, const float* __restrict__ lam_im,
             const float* __restrict__ dt_param, const float* __restrict__ dtp,
             float2* __restrict__ S) {
    int id = blockIdx.x * 256 + threadIdx.x;      // 131072 = B*C*H*W
    int w = id & 63;
    int c = (id >> 12) & 15;
    int b = id >> 16;
    float dte = dtp[0] * sp_f(dt_param[c]);
    float ea = expf(-sp_f(lam_re[c]) * dte);
    float ph = lam_im[c] * dte;
    float Ar = ea * cosf(ph), Ai = ea * sinf(ph);
    if (w > 32) Ai = -Ai;
    bool sc = (w == 0) || (w == 32);
    int pix = id & (NPIX - 1);
    int base = (b * Tt * Cc + c) * NPIX + pix;
    float s1r = 0.f, s1i = 0.f, s2r = 0.f, s2i = 0.f;
    #pragma unroll
    for (int t = 0; t < Tt; ++t) {
        int idx = base + t * (Cc * NPIX);
        float2 zv = Z[idx];
        float nr = Ar * s1r - Ai * s1i + zv.x;
        float ni = Ar * s1i + Ai * s1r + zv.y;
        s1r = nr; s1i = ni;
        float zr, zi;
        if (sc) {
            nr = Ar * s2r + Ai * s2i + zv.x;
            ni = Ar * s2i - Ai * s2r + zv.y;
            s2r = nr; s2i = ni;
            zr = 0.5f * (s1r + s2r); zi = 0.5f * (s1i + s2i);
        } else { zr = s1r; zi = s1i; }
        S[idx] = make_float2(zv.x + zr, zv.y + zi);
    }
}

// ---------------- K5: field = ifft2_std(S) + noise, 512 threads -----------------------
__global__ __launch_bounds__(512)
void k_fft_inv(const float2* __restrict__ Sp,
               const float* __restrict__ noise_r, const float* __restrict__ noise_i,
               const float* __restrict__ sigma_p, const float* __restrict__ dts_p,
               float2* __restrict__ xf) {
    int img = blockIdx.x; int tid = threadIdx.x;
    __shared__ float re[64 * 65], im[64 * 65];
    __shared__ float twr[64], twi[64];
    if (tid < 64) {
        float ang = 0.098174770424681038798f * (float)tid;   // S=+1
        twr[tid] = cosf(ang); twi[tid] = sinf(ang);
    }
    const float2* src = Sp + (size_t)img * NPIX;
    for (int idx = tid; idx < NPIX; idx += 512) {
        int h = idx >> 6, w = idx & 63;
        float2 v = src[idx];
        re[h * 65 + w] = v.x; im[h * 65 + w] = v.y;
    }
    __syncthreads();
    fft2d_r8<1>(re, im, twr, twi, tid);
    float ns = sigma_p[0] * sqrtf(dts_p[0]);
    const float inv = 1.f / 4096.f;
    float2* dst = xf + (size_t)img * NPIX;
    const float* nr = noise_r + (size_t)img * NPIX;
    const float* ni = noise_i + (size_t)img * NPIX;
    for (int idx = tid; idx < NPIX; idx += 512) {
        int h = idx >> 6, w = idx & 63;
        dst[idx] = make_float2(re[h * 65 + w] * inv + ns * nr[idx],
                               im[h * 65 + w] * inv + ns * ni[idx]);
    }
}

// ---------------- K6: PH layer — R7 structure + Jdiff 4-chunk pass 1 ------------------
// 512 blocks x 256 threads; wave owns rows wv*32..+31, all 4 chunks; template-unrolled
// K-loops with depth-2 register prefetch ring; no barriers inside K-loops.
__global__ __launch_bounds__(256, 2)
void k_ph(const float2* __restrict__ field,
          const float* __restrict__ ln_g, const float* __restrict__ ln_b,
          const float* __restrict__ b1, const float* __restrict__ w2,
          const ushort_t* __restrict__ w1n, const ushort_t* __restrict__ w1t,
          const ushort_t* __restrict__ B1f, const ushort_t* __restrict__ B2f,
          const float* __restrict__ dts_p,
          float* __restrict__ out) {
    __shared__ ushort_t xin_s[128 * 40];
    __shared__ ushort_t g_s[128 * 40];
    __shared__ ushort_t pg_s[128 * 40];
    __shared__ ushort_t A_s[128 * 136] __attribute__((aligned(16)));

    int tid = threadIdx.x;
    int bt = blockIdx.x >> 5;
    int pix0 = (blockIdx.x & 31) << 7;

    int p = tid & 127, half = tid >> 7;
    const float2* fbase = field + ((size_t)bt * 16) * NPIX + pix0 + p;
    float2 xv[8];
    float s1 = 0.f, s2 = 0.f;
    #pragma unroll
    for (int j = 0; j < 8; ++j) {
        xv[j] = fbase[(half * 8 + j) * NPIX];
        s1 += xv[j].x + xv[j].y;
        s2 += xv[j].x * xv[j].x + xv[j].y * xv[j].y;
    }
    float2* red = (float2*)A_s;
    red[p * 2 + half] = make_float2(s1, s2);
    __syncthreads();
    float2 r0 = red[p * 2], r1 = red[p * 2 + 1];
    float mu = (r0.x + r1.x) * 0.03125f;
    float var = (r0.y + r1.y) * 0.03125f - mu * mu;
    float rs = rsqrtf(var + 1e-5f);
    #pragma unroll
    for (int j = 0; j < 8; ++j) {
        int cf = half * 8 + j;
        xin_s[p * 40 + cf]      = f2bf((xv[j].x - mu) * rs * ln_g[cf] + ln_b[cf]);
        xin_s[p * 40 + cf + 16] = f2bf((xv[j].y - mu) * rs * ln_g[cf + 16] + ln_b[cf + 16]);
    }
    __syncthreads();

    int lane = tid & 63, wv = tid >> 6;
    int quad = lane >> 4, l15 = lane & 15;
    const f32x4 zero4 = {0.f, 0.f, 0.f, 0.f};
    int m0 = wv * 32;

    // ---- z GEMM: z[rows m0..m0+31][128] = xin @ W1 (K=32) ----
    f32x4 zacc[2][8];
    #pragma unroll
    for (int mt = 0; mt < 2; ++mt)
        #pragma unroll
        for (int nt = 0; nt < 8; ++nt) zacc[mt][nt] = zero4;
    U16 az[2];
    #pragma unroll
    for (int mt = 0; mt < 2; ++mt)
        az[mt].u = *(const uint4*)&xin_s[(m0 + mt * 16 + l15) * 40 + quad * 8];
    #pragma unroll
    for (int nt = 0; nt < 8; ++nt) {
        U16 bz;
        bz.u = *(const uint4*)&w1t[(nt * 16 + l15) * 32 + quad * 8];
        zacc[0][nt] = MFMA16(az[0].s, bz.s, zacc[0][nt]);
        zacc[1][nt] = MFMA16(az[1].s, bz.s, zacc[1][nt]);
    }
    #pragma unroll
    for (int nt = 0; nt < 8; ++nt) {
        int col = nt * 16 + l15;
        float b1v = b1[col], w2v = w2[col];
        #pragma unroll
        for (int mt = 0; mt < 2; ++mt) {
            #pragma unroll
            for (int r = 0; r < 4; ++r) {
                int row = m0 + mt * 16 + quad * 4 + r;
                float z = zacc[mt][nt][r] + b1v;
                float s = 1.f / (1.f + expf(-z));
                float t = s * (1.f + z * (1.f - s)) * w2v;
                A_s[row * 136 + col] = f2bf(t);
            }
        }
    }
    __syncthreads();

    // ---- g GEMM: g[rows][32] = t @ W1^T (K=128) ----
    f32x4 gacc[2][2];
    #pragma unroll
    for (int mt = 0; mt < 2; ++mt)
        #pragma unroll
        for (int nt = 0; nt < 2; ++nt) gacc[mt][nt] = zero4;
    #pragma unroll
    for (int q = 0; q < 4; ++q) {
        U16 ag[2];
        #pragma unroll
        for (int mt = 0; mt < 2; ++mt)
            ag[mt].u = *(const uint4*)&A_s[(m0 + mt * 16 + l15) * 136 + q * 32 + quad * 8];
        #pragma unroll
        for (int nt = 0; nt < 2; ++nt) {
            U16 bg;
            bg.u = *(const uint4*)&w1n[(nt * 16 + l15) * 128 + q * 32 + quad * 8];
            gacc[0][nt] = MFMA16(ag[0].s, bg.s, gacc[0][nt]);
            gacc[1][nt] = MFMA16(ag[1].s, bg.s, gacc[1][nt]);
        }
    }
    #pragma unroll
    for (int mt = 0; mt < 2; ++mt)
        #pragma unroll
        for (int nt = 0; nt < 2; ++nt)
            #pragma unroll
            for (int r = 0; r < 4; ++r)
                g_s[(m0 + mt * 16 + quad * 4 + r) * 40 + nt * 16 + l15] = f2bf(gacc[mt][nt][r]);
    __syncthreads();

    // ---- K-loop setup: LDS row pointers (constexpr per-step offsets), g in regs ----
    const ushort_t* xr0 = &xin_s[(m0 + l15) * 40];
    const ushort_t* xr1 = &xin_s[(m0 + 16 + l15) * 40];
    uint4 gvp0 = *(const uint4*)&g_s[(m0 + l15) * 40 + quad * 8];
    uint4 gvp1 = *(const uint4*)&g_s[(m0 + 16 + l15) * 40 + quad * 8];
    float gf0[8], gf1[8];
    expand8(gvp0, gf0);
    expand8(gvp1, gf1);
    const uint4* B1v = (const uint4*)B1f;
    const uint4* B2v = (const uint4*)B2f;

    // ---- pass 1: [Jd(2ch) | Pg(2ch)] = o @ B1^T, s=0..32 (32 = bias step) ----
    uint4 br[2][4];
    #pragma unroll
    for (int pf = 0; pf < 2; ++pf)
        #pragma unroll
        for (int ch = 0; ch < 4; ++ch)
            br[pf][ch] = B1v[(pf * 4 + ch) * 64 + lane];
    f32x4 acc1[4][2];
    #pragma unroll
    for (int ch = 0; ch < 4; ++ch) { acc1[ch][0] = zero4; acc1[ch][1] = zero4; }
    cunroll<33>([&](auto Sc) {
        constexpr int s = Sc.value;
        constexpr int cur = s & 1;
        U16 a0, a1;
        if constexpr (s < 32) {
            float x0 = bf2f(xr0[s]);
            float x1 = bf2f(xr1[s]);
            a0.u = synth8(gf0, x0);
            a1.u = synth8(gf1, x1);
        } else {
            a0.u = gvp0; a1.u = gvp1;
        }
        #pragma unroll
        for (int ch = 0; ch < 4; ++ch) {
            U16 b; b.u = br[cur][ch];
            acc1[ch][0] = MFMA16(a0.s, b.s, acc1[ch][0]);
            acc1[ch][1] = MFMA16(a1.s, b.s, acc1[ch][1]);
        }
        if constexpr (s + 2 < 33) {
            #pragma unroll
            for (int ch = 0; ch < 4; ++ch)
                br[cur][ch] = B1v[((s + 2) * 4 + ch) * 64 + lane];
        }
    });
    // Pg -> pg_s (own rows)
    #pragma unroll
    for (int mt = 0; mt < 2; ++mt)
        #pragma unroll
        for (int c2 = 0; c2 < 2; ++c2)
            #pragma unroll
            for (int r = 0; r < 4; ++r)
                pg_s[(m0 + mt * 16 + quad * 4 + r) * 40 + c2 * 16 + l15] =
                    f2bf(acc1[2 + c2][mt][r]);
    __syncthreads();

    // ---- pass 2: ptpg(32 cols) = (x (x) pg) @ B2^T ----
    uint4 pgp0 = *(const uint4*)&pg_s[(m0 + l15) * 40 + quad * 8];
    uint4 pgp1 = *(const uint4*)&pg_s[(m0 + 16 + l15) * 40 + quad * 8];
    float pgf0[8], pgf1[8];
    expand8(pgp0, pgf0);
    expand8(pgp1, pgf1);
    uint4 br2[2][2];
    #pragma unroll
    for (int pf = 0; pf < 2; ++pf) {
        br2[pf][0] = B2v[(pf * 2 + 0) * 64 + lane];
        br2[pf][1] = B2v[(pf * 2 + 1) * 64 + lane];
    }
    f32x4 acc2[2][2];
    acc2[0][0] = zero4; acc2[0][1] = zero4; acc2[1][0] = zero4; acc2[1][1] = zero4;
    cunroll<33>([&](auto Sc) {
        constexpr int s = Sc.value;
        constexpr int cur = s & 1;
        U16 a0, a1;
        if constexpr (s < 32) {
            float x0 = bf2f(xr0[s]);
            float x1 = bf2f(xr1[s]);
            a0.u = synth8(pgf0, x0);
            a1.u = synth8(pgf1, x1);
        } else {
            a0.u = pgp0; a1.u = pgp1;
        }
        #pragma unroll
        for (int ch = 0; ch < 2; ++ch) {
            U16 b; b.u = br2[cur][ch];
            acc2[ch][0] = MFMA16(a0.s, b.s, acc2[ch][0]);
            acc2[ch][1] = MFMA16(a1.s, b.s, acc2[ch][1]);
        }
        if constexpr (s + 2 < 33) {
            br2[cur][0] = B2v[((s + 2) * 2 + 0) * 64 + lane];
            br2[cur][1] = B2v[((s + 2) * 2 + 1) * 64 + lane];
        }
    });

    // ---- epilogue: upd = Jd-term - ptpg - 1e-4 g -> LDS f32, combine + write ----
    __syncthreads();
    float* upd = (float*)A_s;
    #pragma unroll
    for (int mt = 0; mt < 2; ++mt) {
        #pragma unroll
        for (int c2 = 0; c2 < 2; ++c2) {
            int col = c2 * 16 + l15;
            #pragma unroll
            for (int r = 0; r < 4; ++r) {
                int row = m0 + mt * 16 + quad * 4 + r;
                float gval = bf2f(g_s[row * 40 + col]);
                upd[row * 33 + col] = acc1[c2][mt][r] - acc2[c2][mt][r] - 1e-4f * gval;
            }
        }
    }
    __syncthreads();
    float dts = dts_p[0];
    #pragma unroll
    for (int cc = 0; cc < 16; ++cc) {
        int c = half * 16 + cc;
        float2 v = fbase[cc * NPIX];
        float xcv = half ? v.y : v.x;
        out[((size_t)bt * 32 + c) * NPIX + pix0 + p] = xcv + dts * upd[p * 33 + c];
    }
}

extern "C" void kernel_launch(void* const* d_in, const int* in_sizes, int n_in,
                              void* d_out, int out_size, void* d_ws, size_t ws_size,
                              hipStream_t stream) {
    const float* x_real   = (const float*)d_in[0];
    const float* x_imag   = (const float*)d_in[1];
    const float* dt       = (const float*)d_in[2];
    const float* conv_w   = (const float*)d_in[3];
    const float* conv_b   = (const float*)d_in[4];
    const float* spec_re  = (const float*)d_in[5];
    const float* spec_im  = (const float*)d_in[6];
    const float* lam_re   = (const float*)d_in[7];
    const float* lam_im   = (const float*)d_in[8];
    const float* dt_param = (const float*)d_in[9];
    const float* sigma    = (const float*)d_in[10];
    const float* noise_r  = (const float*)d_in[11];
    const float* noise_i  = (const float*)d_in[12];
    const float* ln_g     = (const float*)d_in[13];
    const float* ln_b     = (const float*)d_in[14];
    const float* W1       = (const float*)d_in[15];
    const float* b1       = (const float*)d_in[16];
    const float* w2       = (const float*)d_in[17];
    const float* Jg_W     = (const float*)d_in[19];
    const float* Jg_b     = (const float*)d_in[20];
    const float* Rg_W     = (const float*)d_in[21];
    const float* Rg_b     = (const float*)d_in[22];

    float2* wsA = (float2*)d_ws;              // x1, later final field
    float2* wsB = wsA + 1048576;              // Z spectrum
    float2* wsS = wsB + 1048576;              // assembled spectrum S

    ushort_t* B1f = (ushort_t*)(wsS + 1048576);
    ushort_t* B2f = B1f + 33 * 2048;
    ushort_t* w1n = B2f + 33 * 1024;
    ushort_t* w1t = w1n + 4096;
    float*    dts = (float*)(w1t + 4096);

    k_conv<<<552, 256, 0, stream>>>(x_real, x_imag, conv_w, conv_b, wsA,
                                    Jg_W, Jg_b, Rg_W, Rg_b, W1, dt, dt_param,
                                    B1f, B2f, w1n, w1t, dts);
    k_fft_fwd<<<NIMG, 512, 0, stream>>>(wsA, spec_re, spec_im, wsB);
    k_scan2<<<512, 256, 0, stream>>>(wsB, lam_re, lam_im, dt_param, dt, wsS);
    k_fft_inv<<<NIMG, 512, 0, stream>>>(wsS, noise_r, noise_i, sigma, dts, wsA);
    k_ph<<<512, 256, 0, stream>>>(wsA, ln_g, ln_b, b1, w2, w1n, w1t, B1f, B2f, dts,
                                  (float*)d_out);
}